// Round 8
// baseline (795.193 us; speedup 1.0000x reference)
//
#include <hip/hip_runtime.h>

typedef _Float16 f16;
typedef _Float16 f16x8 __attribute__((ext_vector_type(8)));
typedef float f32x4 __attribute__((ext_vector_type(4)));

#define MFMA16(a, b, c) __builtin_amdgcn_mfma_f32_16x16x32_f16(a, b, c, 0, 0, 0)

// LDS layout (byte offsets), 128 KiB total.
#define H0H 0
#define H0L 32768
#define H1H 65536
#define H1L 98304
#define H2H 0
#define H2L 16384
#define LGO 32768
#define PRO 47104
#define SMEM_BYTES 131072

// ---------------- prep: hi/lo split-transpose of weights ----------------
__global__ void k_tr2(const float* __restrict__ W, f16* __restrict__ Whi,
                      f16* __restrict__ Wlo, int K, int N, int lgKp) {
  int t = blockIdx.x * 256 + threadIdx.x;
  int n = t >> lgKp, k = t & ((1 << lgKp) - 1);
  float v = (k < K && n < N) ? W[k * N + n] : 0.f;
  f16 h = (f16)v;
  f16 l = (f16)(v - (float)h);
  Whi[t] = h;
  Wlo[t] = l;
}

// ---------------- fused MLP (double-f16) + C51 projection ----------------

template <int KSTEPS, int NT, int SBIN>
__device__ __forceinline__ void layer_hilo(const char* sm, int inH, int inL,
                                           const f16* __restrict__ wh,
                                           const f16* __restrict__ wl, int ldw,
                                           int nbase, int kbase, int lr, int ls,
                                           f32x4 (&acc)[NT][2]) {
  const int xr = (lr & 7) << 4;
  const char* pH0 = sm + inH + lr * SBIN;
  const char* pH1 = sm + inH + (lr + 16) * SBIN;
  const char* pL0 = sm + inL + lr * SBIN;
  const char* pL1 = sm + inL + (lr + 16) * SBIN;
#pragma unroll
  for (int ks = 0; ks < KSTEPS; ++ks) {
    int cb = (ks * 64 + ls * 16) ^ xr;
    f16x8 ah0 = *(const f16x8*)(pH0 + cb);
    f16x8 ah1 = *(const f16x8*)(pH1 + cb);
    f16x8 al0 = *(const f16x8*)(pL0 + cb);
    f16x8 al1 = *(const f16x8*)(pL1 + cb);
    int gk = kbase + ks * 32 + ls * 8;
#pragma unroll
    for (int nt = 0; nt < NT; ++nt) {
      int wrow = nbase + nt * 16 + lr;
      f16x8 bh = *(const f16x8*)(wh + (size_t)wrow * ldw + gk);
      f16x8 bl = *(const f16x8*)(wl + (size_t)wrow * ldw + gk);
      acc[nt][0] = MFMA16(ah0, bh, acc[nt][0]);
      acc[nt][1] = MFMA16(ah1, bh, acc[nt][1]);
      acc[nt][0] = MFMA16(al0, bh, acc[nt][0]);
      acc[nt][1] = MFMA16(al1, bh, acc[nt][1]);
      acc[nt][0] = MFMA16(ah0, bl, acc[nt][0]);
      acc[nt][1] = MFMA16(ah1, bl, acc[nt][1]);
    }
  }
}

template <int NT>
__device__ __forceinline__ void epi_split(char* sm, int outH, int outL, int sbout,
                                          const float* __restrict__ bias, int nbias,
                                          int colbase, int lr, int ls,
                                          f32x4 (&acc)[NT][2]) {
#pragma unroll
  for (int nt = 0; nt < NT; ++nt) {
    int gcol = nbias + nt * 16 + lr;
    int lcol = colbase + nt * 16 + lr;
    float bv = bias[gcol];
    int cb = lcol * 2;
#pragma unroll
    for (int r = 0; r < 4; ++r) {
      int row = ls * 4 + r;
      int xr = (row & 7) << 4;
      int o0 = row * sbout + (cb ^ xr);
      int o1 = (row + 16) * sbout + (cb ^ xr);
      float v0 = fmaxf(acc[nt][0][r] + bv, 0.f);
      float v1 = fmaxf(acc[nt][1][r] + bv, 0.f);
      f16 h0 = (f16)v0, l0 = (f16)(v0 - (float)h0);
      f16 h1 = (f16)v1, l1 = (f16)(v1 - (float)h1);
      *(f16*)(sm + outH + o0) = h0;
      *(f16*)(sm + outL + o0) = l0;
      *(f16*)(sm + outH + o1) = h1;
      *(f16*)(sm + outL + o1) = l1;
    }
  }
}

__global__ __launch_bounds__(512, 2) void k_fused(
    const float* __restrict__ obs, const float* __restrict__ act,
    const f16* __restrict__ w0h, const f16* __restrict__ w0l,
    const f16* __restrict__ w1h, const f16* __restrict__ w1l,
    const f16* __restrict__ w2h, const f16* __restrict__ w2l,
    const f16* __restrict__ w3h, const f16* __restrict__ w3l,
    const float* __restrict__ b0p, const float* __restrict__ b1p,
    const float* __restrict__ b2p, const float* __restrict__ b3p,
    const float* __restrict__ rew, const float* __restrict__ boot,
    const float* __restrict__ disc, const float* __restrict__ qsup,
    float* __restrict__ out) {
  __shared__ __align__(16) char sm[SMEM_BYTES];
  const int tid = threadIdx.x;
  const int wv = tid >> 6, l = tid & 63;
  const int lr = l & 15, ls = l >> 4;
  const int r0 = blockIdx.x * 32;

  // ---- exact hi/lo A-fragments for layer 1, from f32 obs/act ----
  f16x8 xh[2][2], xl[2][2];
#pragma unroll
  for (int h = 0; h < 2; ++h) {
    int grow = r0 + h * 16 + lr;
    const float* ob = obs + (size_t)grow * 48;
    const float* ac = act + (size_t)grow * 12;
    float f[2][8];
#pragma unroll
    for (int i = 0; i < 8; ++i) f[0][i] = ob[ls * 8 + i];
    if (ls < 2) {
#pragma unroll
      for (int i = 0; i < 8; ++i) f[1][i] = ob[32 + ls * 8 + i];
    } else if (ls == 2) {
#pragma unroll
      for (int i = 0; i < 8; ++i) f[1][i] = ac[i];
    } else {
#pragma unroll
      for (int i = 0; i < 8; ++i) f[1][i] = (i < 4) ? ac[8 + i] : 0.f;
    }
#pragma unroll
    for (int k = 0; k < 2; ++k)
#pragma unroll
      for (int i = 0; i < 8; ++i) {
        f16 hh = (f16)f[k][i];
        xh[h][k][i] = hh;
        xl[h][k][i] = (f16)(f[k][i] - (float)hh);
      }
  }

  auto layer1_panel = [&](int p) {
#pragma unroll
    for (int nt = 0; nt < 4; ++nt) {
      int n0 = p * 512 + wv * 64 + nt * 16;
      const f16* bh0 = w0h + (size_t)(n0 + lr) * 64 + ls * 8;
      const f16* bl0 = w0l + (size_t)(n0 + lr) * 64 + ls * 8;
      f32x4 c0 = {0.f, 0.f, 0.f, 0.f}, c1 = {0.f, 0.f, 0.f, 0.f};
#pragma unroll
      for (int k = 0; k < 2; ++k) {
        f16x8 bh = *(const f16x8*)(bh0 + k * 32);
        f16x8 bl = *(const f16x8*)(bl0 + k * 32);
        c0 = MFMA16(xh[0][k], bh, c0);
        c0 = MFMA16(xl[0][k], bh, c0);
        c0 = MFMA16(xh[0][k], bl, c0);
        c1 = MFMA16(xh[1][k], bh, c1);
        c1 = MFMA16(xl[1][k], bh, c1);
        c1 = MFMA16(xh[1][k], bl, c1);
      }
      float bv = b0p[n0 + lr];
      int cb = (wv * 64 + nt * 16 + lr) * 2;
#pragma unroll
      for (int r = 0; r < 4; ++r) {
        int row = ls * 4 + r;
        int xr2 = (row & 7) << 4;
        int o0 = row * 1024 + (cb ^ xr2);
        int o1 = (row + 16) * 1024 + (cb ^ xr2);
        float v0 = fmaxf(c0[r] + bv, 0.f);
        float v1 = fmaxf(c1[r] + bv, 0.f);
        f16 h0 = (f16)v0, l0 = (f16)(v0 - (float)h0);
        f16 h1 = (f16)v1, l1 = (f16)(v1 - (float)h1);
        *(f16*)(sm + H0H + o0) = h0;
        *(f16*)(sm + H0L + o0) = l0;
        *(f16*)(sm + H0H + o1) = h1;
        *(f16*)(sm + H0L + o1) = l1;
      }
    }
  };

  // ---- layers 1+2, K-panel pipelined ----
  f32x4 acc2[4][2];
#pragma unroll
  for (int nt = 0; nt < 4; ++nt)
    acc2[nt][0] = acc2[nt][1] = (f32x4){0.f, 0.f, 0.f, 0.f};

  layer1_panel(0);
  __syncthreads();
  layer_hilo<16, 4, 1024>(sm, H0H, H0L, w1h, w1l, 1024, wv * 64, 0, lr, ls, acc2);
  __syncthreads();
  layer1_panel(1);
  __syncthreads();
  layer_hilo<16, 4, 1024>(sm, H0H, H0L, w1h, w1l, 1024, wv * 64, 512, lr, ls, acc2);
  epi_split<4>(sm, H1H, H1L, 1024, b1p, wv * 64, wv * 64, lr, ls, acc2);
  __syncthreads();

  // ---- layer 3 ----
  f32x4 acc3[2][2];
#pragma unroll
  for (int nt = 0; nt < 2; ++nt)
    acc3[nt][0] = acc3[nt][1] = (f32x4){0.f, 0.f, 0.f, 0.f};
  layer_hilo<16, 2, 1024>(sm, H1H, H1L, w2h, w2l, 512, wv * 32, 0, lr, ls, acc3);
  for (int i = tid; i < 32 * 104; i += 512) ((float*)(sm + PRO))[i] = 0.f;
  epi_split<2>(sm, H2H, H2L, 512, b2p, wv * 32, wv * 32, lr, ls, acc3);
  __syncthreads();

  // ---- layer 4 -> logits f32 ----
  if (wv < 7) {
    f32x4 acc4[1][2];
    acc4[0][0] = acc4[0][1] = (f32x4){0.f, 0.f, 0.f, 0.f};
    layer_hilo<8, 1, 512>(sm, H2H, H2L, w3h, w3l, 256, wv * 16, 0, lr, ls, acc4);
    int col = wv * 16 + lr;
    float bv = (col < 101) ? b3p[col] : 0.f;
    float* Lg = (float*)(sm + LGO);
#pragma unroll
    for (int r = 0; r < 4; ++r) {
      int row = ls * 4 + r;
      Lg[row * 112 + col] = acc4[0][0][r] + bv;
      Lg[(row + 16) * 112 + col] = acc4[0][1][r] + bv;
    }
  }
  __syncthreads();

  // ---- softmax (f32) + C51 projection (f32, reciprocal-multiply b) ----
  {
    int r = tid >> 4, s = tid & 15;
    int rg = r0 + r;
    const float* Lg = (const float*)(sm + LGO);
    float* Pr = (float*)(sm + PRO);
    float lv[7];
    float mx = -3.4e38f;
#pragma unroll
    for (int i = 0; i < 7; ++i) {
      int j = s + 16 * i;
      float x = (j < 101) ? Lg[r * 112 + j] : -3.4e38f;
      lv[i] = x;
      mx = fmaxf(mx, x);
    }
    mx = fmaxf(mx, __shfl_xor(mx, 1));
    mx = fmaxf(mx, __shfl_xor(mx, 2));
    mx = fmaxf(mx, __shfl_xor(mx, 4));
    mx = fmaxf(mx, __shfl_xor(mx, 8));
    float smv = 0.f;
#pragma unroll
    for (int i = 0; i < 7; ++i) {
      float e = expf(lv[i] - mx);
      lv[i] = e;
      if (s + 16 * i < 101) smv += e;
    }
    smv += __shfl_xor(smv, 1);
    smv += __shfl_xor(smv, 2);
    smv += __shfl_xor(smv, 4);
    smv += __shfl_xor(smv, 8);

    // f32 chain, numpy op-by-op: tz = rew + (boot*disc)*q (separate roundings);
    // b = (tz - V_MIN) * (1/delta_z). Note 1/0.2 rounds to EXACTLY 5.0 in both
    // f32 and f64, so a reciprocal-precomputing reference multiplies by 5.0f —
    // which differs from IEEE /0.2f by 1 ulp on ~30% of operands (the R1/R3
    // orphan-site evidence points exactly here).
    float rw = rew[rg];
    float bd = __fmul_rn(boot[rg], disc[rg]);
#pragma unroll
    for (int i = 0; i < 7; ++i) {
      int j = s + 16 * i;
      if (j < 101) {
        float p = __fdiv_rn(lv[i], smv);
        float tz = __fadd_rn(rw, __fmul_rn(bd, qsup[j]));
        tz = fminf(fmaxf(tz, -10.f), 10.f);
        float bb = __fmul_rn(__fsub_rn(tz, -10.f), 5.0f);
        float fl = floorf(bb), cu = ceilf(bb);
        int li = (int)fl, ui = (int)cu;
        int l2 = li, u2 = ui;
        if (li == ui) {
          if (ui > 0) l2 = li - 1;
          if (li < 100) u2 = ui + 1;
        }
        atomicAdd(&Pr[r * 104 + l2], __fmul_rn(p, __fsub_rn((float)u2, bb)));
        atomicAdd(&Pr[r * 104 + u2], __fmul_rn(p, __fsub_rn(bb, (float)l2)));
      }
    }
  }
  __syncthreads();

  for (int i = tid; i < 32 * 101; i += 512) {
    int r = i / 101, j = i - r * 101;
    out[(size_t)(r0 + r) * 101 + j] = ((const float*)(sm + PRO))[r * 104 + j];
  }
}

// ---------------- launch ----------------

extern "C" void kernel_launch(void* const* d_in, const int* in_sizes, int n_in,
                              void* d_out, int out_size, void* d_ws, size_t ws_size,
                              hipStream_t stream) {
  const float* obs  = (const float*)d_in[0];
  const float* act  = (const float*)d_in[1];
  const float* rew  = (const float*)d_in[2];
  const float* boot = (const float*)d_in[3];
  const float* disc = (const float*)d_in[4];
  const float* qsup = (const float*)d_in[5];
  const float* W0 = (const float*)d_in[6];  const float* b0 = (const float*)d_in[7];
  const float* W1 = (const float*)d_in[8];  const float* b1 = (const float*)d_in[9];
  const float* W2 = (const float*)d_in[10]; const float* b2 = (const float*)d_in[11];
  const float* W3 = (const float*)d_in[12]; const float* b3 = (const float*)d_in[13];

  char* ws = (char*)d_ws;
  f16* w0h = (f16*)(ws);
  f16* w0l = (f16*)(ws + 131072);
  f16* w1h = (f16*)(ws + 262144);
  f16* w1l = (f16*)(ws + 1310720);
  f16* w2h = (f16*)(ws + 2359296);
  f16* w2l = (f16*)(ws + 2621440);
  f16* w3h = (f16*)(ws + 2883584);
  f16* w3l = (f16*)(ws + 2940928);

  k_tr2<<<256, 256, 0, stream>>>(W0, w0h, w0l, 60, 1024, 6);
  k_tr2<<<2048, 256, 0, stream>>>(W1, w1h, w1l, 1024, 512, 10);
  k_tr2<<<512, 256, 0, stream>>>(W2, w2h, w2l, 512, 256, 9);
  k_tr2<<<112, 256, 0, stream>>>(W3, w3h, w3l, 256, 101, 8);

  k_fused<<<2048, 512, 0, stream>>>(obs, act, w0h, w0l, w1h, w1l, w2h, w2l,
                                    w3h, w3l, b0, b1, b2, b3,
                                    rew, boot, disc, qsup, (float*)d_out);
}

// Round 10
// 447.016 us; speedup vs baseline: 1.7789x; 1.7789x over previous
//
#include <hip/hip_runtime.h>

typedef _Float16 f16;
typedef _Float16 f16x8 __attribute__((ext_vector_type(8)));
typedef float f32x4 __attribute__((ext_vector_type(4)));

#define MFMA16(a, b, c) __builtin_amdgcn_mfma_f32_16x16x32_f16(a, b, c, 0, 0, 0)

// LDS layout (byte offsets), 64 KiB total -> 2 blocks/CU.
// Phase A: h0 panel [32][512] f16 @0 (32K), h1 [32][512] f16 @32768 (32K)
// Phase B: h2 [32][256] f16 @0 (16K), logits f32 [32][112] @16384 (ends 30720),
//          proj f32 [32][104] @32768 (in dead-h1 region, zeroed after L3 barrier)
#define H0 0
#define H1 32768
#define H2 0
#define LGO 16384
#define PRO 32768
#define SMEM_BYTES 65536

// ---------------- prep: transpose-cast weights to f16 ----------------
// Wt[n][k] = (f16)W[k][n], K padded to 2^lgKp.
__global__ void k_tr(const float* __restrict__ W, f16* __restrict__ Wt,
                     int K, int N, int lgKp) {
  int t = blockIdx.x * 256 + threadIdx.x;
  int n = t >> lgKp, k = t & ((1 << lgKp) - 1);
  float v = (k < K && n < N) ? W[k * N + n] : 0.f;
  Wt[t] = (f16)v;
}

// ---------------- fused MLP (f16) + C51 projection ----------------

// A from swizzled LDS, B (weights) from global; register-pipelined K loop.
template <int KSTEPS, int NT, int SBIN>
__device__ __forceinline__ void layer_f16(const char* sm, int inOff,
                                          const f16* __restrict__ wt, int ldw,
                                          int nbase, int kbase, int lr, int ls,
                                          f32x4 (&acc)[NT][2]) {
  const int xr = (lr & 7) << 4;
  const char* p0 = sm + inOff + lr * SBIN;
  const char* p1 = sm + inOff + (lr + 16) * SBIN;
  const f16* wb = wt + (size_t)(nbase + lr) * ldw + kbase + ls * 8;

  f16x8 a0A, a1A, bA[NT];
  {
    int cb = (ls * 16) ^ xr;
    a0A = *(const f16x8*)(p0 + cb);
    a1A = *(const f16x8*)(p1 + cb);
#pragma unroll
    for (int nt = 0; nt < NT; ++nt) bA[nt] = *(const f16x8*)(wb + nt * 16 * ldw);
  }
#pragma unroll
  for (int ks = 0; ks < KSTEPS; ++ks) {
    f16x8 a0B, a1B, bB[NT];
    if (ks + 1 < KSTEPS) {  // prefetch next K-step while MFMAs run
      int cb = ((ks + 1) * 64 + ls * 16) ^ xr;
      a0B = *(const f16x8*)(p0 + cb);
      a1B = *(const f16x8*)(p1 + cb);
#pragma unroll
      for (int nt = 0; nt < NT; ++nt)
        bB[nt] = *(const f16x8*)(wb + nt * 16 * ldw + (ks + 1) * 32);
    }
#pragma unroll
    for (int nt = 0; nt < NT; ++nt) {
      acc[nt][0] = MFMA16(a0A, bA[nt], acc[nt][0]);
      acc[nt][1] = MFMA16(a1A, bA[nt], acc[nt][1]);
    }
    a0A = a0B; a1A = a1B;
#pragma unroll
    for (int nt = 0; nt < NT; ++nt) bA[nt] = bB[nt];
  }
}

// bias + relu + f16 cast -> swizzled LDS
template <int NT>
__device__ __forceinline__ void epi_f16(char* sm, int outOff, int sbout,
                                        const float* __restrict__ bias, int nbias,
                                        int colbase, int lr, int ls,
                                        f32x4 (&acc)[NT][2]) {
#pragma unroll
  for (int nt = 0; nt < NT; ++nt) {
    float bv = bias[nbias + nt * 16 + lr];
    int cb = (colbase + nt * 16 + lr) * 2;
#pragma unroll
    for (int r = 0; r < 4; ++r) {
      int row = ls * 4 + r;
      int xr = (row & 7) << 4;
      int o0 = row * sbout + (cb ^ xr);
      int o1 = (row + 16) * sbout + (cb ^ xr);
      *(f16*)(sm + outOff + o0) = (f16)fmaxf(acc[nt][0][r] + bv, 0.f);
      *(f16*)(sm + outOff + o1) = (f16)fmaxf(acc[nt][1][r] + bv, 0.f);
    }
  }
}

__global__ __launch_bounds__(512, 4) void k_fused(
    const float* __restrict__ obs, const float* __restrict__ act,
    const f16* __restrict__ w0t, const f16* __restrict__ w1t,
    const f16* __restrict__ w2t, const f16* __restrict__ w3t,
    const float* __restrict__ b0p, const float* __restrict__ b1p,
    const float* __restrict__ b2p, const float* __restrict__ b3p,
    const float* __restrict__ rew, const float* __restrict__ boot,
    const float* __restrict__ disc, const float* __restrict__ qsup,
    float* __restrict__ out) {
  __shared__ __align__(16) char sm[SMEM_BYTES];
  const int tid = threadIdx.x;
  const int wv = tid >> 6, l = tid & 63;
  const int lr = l & 15, ls = l >> 4;
  const int r0 = blockIdx.x * 32;

  // ---- layer-1 A-fragments from f32 obs/act (cast f16) ----
  f16x8 xh[2][2];  // [row half][k step]
#pragma unroll
  for (int h = 0; h < 2; ++h) {
    int grow = r0 + h * 16 + lr;
    const float* ob = obs + (size_t)grow * 48;
    const float* ac = act + (size_t)grow * 12;
    float f[2][8];
#pragma unroll
    for (int i = 0; i < 8; ++i) f[0][i] = ob[ls * 8 + i];
    if (ls < 2) {
#pragma unroll
      for (int i = 0; i < 8; ++i) f[1][i] = ob[32 + ls * 8 + i];
    } else if (ls == 2) {
#pragma unroll
      for (int i = 0; i < 8; ++i) f[1][i] = ac[i];
    } else {
#pragma unroll
      for (int i = 0; i < 8; ++i) f[1][i] = (i < 4) ? ac[8 + i] : 0.f;
    }
#pragma unroll
    for (int k = 0; k < 2; ++k)
#pragma unroll
      for (int i = 0; i < 8; ++i) xh[h][k][i] = (f16)f[k][i];
  }

  // layer-1 panel p: N-cols [p*512, p*512+512) -> h0 (local cols 0..511)
  auto layer1_panel = [&](int p) {
#pragma unroll
    for (int nt = 0; nt < 4; ++nt) {
      int n0 = p * 512 + wv * 64 + nt * 16;
      const f16* b0 = w0t + (size_t)(n0 + lr) * 64 + ls * 8;
      f32x4 c0 = {0.f, 0.f, 0.f, 0.f}, c1 = {0.f, 0.f, 0.f, 0.f};
#pragma unroll
      for (int k = 0; k < 2; ++k) {
        f16x8 bh = *(const f16x8*)(b0 + k * 32);
        c0 = MFMA16(xh[0][k], bh, c0);
        c1 = MFMA16(xh[1][k], bh, c1);
      }
      float bv = b0p[n0 + lr];
      int cb = (wv * 64 + nt * 16 + lr) * 2;
#pragma unroll
      for (int r = 0; r < 4; ++r) {
        int row = ls * 4 + r;
        int xr2 = (row & 7) << 4;
        *(f16*)(sm + H0 + row * 1024 + (cb ^ xr2)) = (f16)fmaxf(c0[r] + bv, 0.f);
        *(f16*)(sm + H0 + (row + 16) * 1024 + (cb ^ xr2)) = (f16)fmaxf(c1[r] + bv, 0.f);
      }
    }
  };

  // ---- layers 1+2, K-panel pipelined (h1 acc in registers) ----
  f32x4 acc2[4][2];
#pragma unroll
  for (int nt = 0; nt < 4; ++nt)
    acc2[nt][0] = acc2[nt][1] = (f32x4){0.f, 0.f, 0.f, 0.f};

  layer1_panel(0);
  __syncthreads();
  layer_f16<16, 4, 1024>(sm, H0, w1t, 1024, wv * 64, 0, lr, ls, acc2);
  __syncthreads();
  layer1_panel(1);
  __syncthreads();
  layer_f16<16, 4, 1024>(sm, H0, w1t, 1024, wv * 64, 512, lr, ls, acc2);
  epi_f16<4>(sm, H1, 1024, b1p, wv * 64, wv * 64, lr, ls, acc2);
  __syncthreads();  // h0 reads done; h1 complete

  // ---- layer 3: K=512, N=256 -> h2 (reusing h0 region) ----
  f32x4 acc3[2][2];
#pragma unroll
  for (int nt = 0; nt < 2; ++nt)
    acc3[nt][0] = acc3[nt][1] = (f32x4){0.f, 0.f, 0.f, 0.f};
  layer_f16<16, 2, 1024>(sm, H1, w2t, 512, wv * 32, 0, lr, ls, acc3);
  epi_f16<2>(sm, H2, 512, b2p, wv * 32, wv * 32, lr, ls, acc3);
  __syncthreads();  // h1 reads done; h2 complete

  // zero projection bins (in dead-h1 region; consumed after next barrier)
  for (int i = tid; i < 32 * 104; i += 512) ((float*)(sm + PRO))[i] = 0.f;

  // ---- layer 4: K=256, N=112 (7 tiles, waves 0..6) -> logits f32 ----
  if (wv < 7) {
    f32x4 acc4[1][2];
    acc4[0][0] = acc4[0][1] = (f32x4){0.f, 0.f, 0.f, 0.f};
    layer_f16<8, 1, 512>(sm, H2, w3t, 256, wv * 16, 0, lr, ls, acc4);
    int col = wv * 16 + lr;
    float bv = (col < 101) ? b3p[col] : 0.f;
    float* Lg = (float*)(sm + LGO);
#pragma unroll
    for (int r = 0; r < 4; ++r) {
      int row = ls * 4 + r;
      Lg[row * 112 + col] = acc4[0][0][r] + bv;
      Lg[(row + 16) * 112 + col] = acc4[0][1][r] + bv;
    }
  }
  __syncthreads();

  // ---- softmax (f32) + C51 projection (f32, reciprocal-multiply b) ----
  {
    int r = tid >> 4, s = tid & 15;
    int rg = r0 + r;
    const float* Lg = (const float*)(sm + LGO);
    float* Pr = (float*)(sm + PRO);
    float lv[7];
    float mx = -3.4e38f;
#pragma unroll
    for (int i = 0; i < 7; ++i) {
      int j = s + 16 * i;
      float x = (j < 101) ? Lg[r * 112 + j] : -3.4e38f;
      lv[i] = x;
      mx = fmaxf(mx, x);
    }
    mx = fmaxf(mx, __shfl_xor(mx, 1));
    mx = fmaxf(mx, __shfl_xor(mx, 2));
    mx = fmaxf(mx, __shfl_xor(mx, 4));
    mx = fmaxf(mx, __shfl_xor(mx, 8));
    float smv = 0.f;
#pragma unroll
    for (int i = 0; i < 7; ++i) {
      float e = expf(lv[i] - mx);
      lv[i] = e;
      if (s + 16 * i < 101) smv += e;
    }
    smv += __shfl_xor(smv, 1);
    smv += __shfl_xor(smv, 2);
    smv += __shfl_xor(smv, 4);
    smv += __shfl_xor(smv, 8);

    // Verified-match chain (R8): tz = rew + (boot*disc)*q, clip,
    // b = (tz - V_MIN) * 5.0f   [1/delta_z == 5.0 exactly]
    float rw = rew[rg];
    float bd = __fmul_rn(boot[rg], disc[rg]);
#pragma unroll
    for (int i = 0; i < 7; ++i) {
      int j = s + 16 * i;
      if (j < 101) {
        float p = __fdiv_rn(lv[i], smv);
        float tz = __fadd_rn(rw, __fmul_rn(bd, qsup[j]));
        tz = fminf(fmaxf(tz, -10.f), 10.f);
        float bb = __fmul_rn(__fsub_rn(tz, -10.f), 5.0f);
        float fl = floorf(bb), cu = ceilf(bb);
        int li = (int)fl, ui = (int)cu;
        int l2 = li, u2 = ui;
        if (li == ui) {
          if (ui > 0) l2 = li - 1;
          if (li < 100) u2 = ui + 1;
        }
        atomicAdd(&Pr[r * 104 + l2], __fmul_rn(p, __fsub_rn((float)u2, bb)));
        atomicAdd(&Pr[r * 104 + u2], __fmul_rn(p, __fsub_rn(bb, (float)l2)));
      }
    }
  }
  __syncthreads();

  for (int i = tid; i < 32 * 101; i += 512) {
    int r = i / 101, j = i - r * 101;
    out[(size_t)(r0 + r) * 101 + j] = ((const float*)(sm + PRO))[r * 104 + j];
  }
}

// ---------------- launch ----------------

extern "C" void kernel_launch(void* const* d_in, const int* in_sizes, int n_in,
                              void* d_out, int out_size, void* d_ws, size_t ws_size,
                              hipStream_t stream) {
  const float* obs  = (const float*)d_in[0];
  const float* act  = (const float*)d_in[1];
  const float* rew  = (const float*)d_in[2];
  const float* boot = (const float*)d_in[3];
  const float* disc = (const float*)d_in[4];
  const float* qsup = (const float*)d_in[5];
  const float* W0 = (const float*)d_in[6];  const float* b0 = (const float*)d_in[7];
  const float* W1 = (const float*)d_in[8];  const float* b1 = (const float*)d_in[9];
  const float* W2 = (const float*)d_in[10]; const float* b2 = (const float*)d_in[11];
  const float* W3 = (const float*)d_in[12]; const float* b3 = (const float*)d_in[13];

  char* ws = (char*)d_ws;
  f16* w0t = (f16*)(ws);             // [1024][64]  131072 B
  f16* w1t = (f16*)(ws + 131072);    // [512][1024] 1048576 B
  f16* w2t = (f16*)(ws + 1179648);   // [256][512]  262144 B
  f16* w3t = (f16*)(ws + 1441792);   // [112][256]  57344 B  (end 1499136)

  k_tr<<<256, 256, 0, stream>>>(W0, w0t, 60, 1024, 6);
  k_tr<<<2048, 256, 0, stream>>>(W1, w1t, 1024, 512, 10);
  k_tr<<<512, 256, 0, stream>>>(W2, w2t, 512, 256, 9);
  k_tr<<<112, 256, 0, stream>>>(W3, w3t, 256, 101, 8);

  k_fused<<<2048, 512, 0, stream>>>(obs, act, w0t, w1t, w2t, w3t,
                                    b0, b1, b2, b3,
                                    rew, boot, disc, qsup, (float*)d_out);
}